// Round 9
// baseline (36.415 us; speedup 1.0000x reference)
//
#include <hip/hip_runtime.h>

#define IMH 384
#define IMW 384
#define OH 378
#define OW 378
#define NB 64
#define SROWS 21
#define INROWS 27          // SROWS + 6
#define NSTRIP 18          // 18*21 = 378 exactly
#define BLOCK 256          // 4 waves; each wave = independent task
#define SEGW 104           // output cols per wave (4 DPP groups x 26)
#define WINF 128           // staged floats per row per tensor per wave
#define RING 8             // ring slots (rows) per tensor per wave
#define LA 6               // rows of DMA lookahead (4 DMAs each)

// Round 18: R17 (counted-vmcnt DMA ring) = 28.2us, short of 17-22 pred.
// VALU floor ~6us, HBM floor ~9-15us (R11 capture: FETCH only 54MB) ->
// neither pipe is the wall. Surviving theory: PHASE-LOCKED STALLS. Every
// prior design barriers 4 waves per row x 27 rows; all 1152 blocks start
// together with identical phase lengths, so all ~20 waves/CU hit their
// lgkm/vmcnt waits simultaneously -> TLP hides nothing. Explains R12/R13/
// R14/R17 flatness.
// Fix: wave-independent dataflow. Wave = (b, strip, 104-col seg) with a
// PRIVATE 8KB LDS ring (4x8KB = 32KB/block, 5 blocks/CU, 20 waves/CU).
// Producer == consumer == wave -> completion tracked by own vmcnt, ZERO
// barriers in the main loop; waves de-phase naturally. 4 size-4 DMAs/row
// (2 chunks x 2 tensors), LA=6, steady wait vmcnt(24), never 0 mid-loop.
// Seg windows {0,104,208,256}: all reads in-image, no OOB anywhere.
// Cost: seg3 ~35% dead lanes (~9% device VALU) - acceptable vs de-phasing.
// PRED: LDS 32768, VGPR 56-72; 18-22us if phase-lock was the wall; flat
// ~28 -> per-row serial chain structural -> R19 = 2 rows/iter.

template <int CTRL>
__device__ __forceinline__ float dpp_sh(float v) {
    return __int_as_float(__builtin_amdgcn_update_dpp(
        0, __float_as_int(v), CTRL, 0xf, 0xf, true));
}

__device__ __forceinline__ float2 f2add(float2 a, float2 b) { return make_float2(a.x + b.x, a.y + b.y); }
__device__ __forceinline__ float2 f2sub(float2 a, float2 b) { return make_float2(a.x - b.x, a.y - b.y); }
__device__ __forceinline__ float2 f2mul(float2 a, float2 b) { return make_float2(a.x * b.x, a.y * b.y); }
__device__ __forceinline__ float2 f2fma(float2 a, float2 b, float2 c) {
    return make_float2(fmaf(a.x, b.x, c.x), fmaf(a.y, b.y, c.y));
}
__device__ __forceinline__ float2 f2fnma(float2 a, float2 b, float2 c) {  // c - a*b
    return make_float2(fmaf(-a.x, b.x, c.x), fmaf(-a.y, b.y, c.y));
}
__device__ __forceinline__ float2 f2fms(float2 a, float s, float2 c) {    // a*s - c
    return make_float2(fmaf(a.x, s, -c.x), fmaf(a.y, s, -c.y));
}
__device__ __forceinline__ float2 f2s(float s) { return make_float2(s, s); }

// async global->LDS DMA, 4B per lane; dest = wave-uniform base + lane*4B
__device__ __forceinline__ void stage4(const float* g, float* l) {
    __builtin_amdgcn_global_load_lds(
        (const __attribute__((address_space(1))) uint32_t*)(g),
        (__attribute__((address_space(3))) uint32_t*)(l),
        4, 0, 0);
}

#define WAITV(n) asm volatile("s_waitcnt vmcnt(" #n ")" ::: "memory")

__global__ __launch_bounds__(BLOCK)
__attribute__((amdgpu_waves_per_eu(5, 8)))
void ssim_kernel(
    const float* __restrict__ X, const float* __restrict__ Y,
    const float* __restrict__ data_range, float* __restrict__ partials)
{
    const int tid   = threadIdx.x;
    const int wv    = tid >> 6;               // wave 0..3 = column segment
    const int ln    = tid & 63;
    const int g4    = ln >> 4;                // DPP group 0..3 within wave
    const int j     = ln & 15;                // lane within group
    const int strip = blockIdx.x;
    const int b     = blockIdx.y;
    const int y0    = strip * SROWS;          // <= 357; +26 = 383 in range

    // per-wave private ring: [wave][tensor][slot][floats]
    __shared__ float lds[4][2][RING][WINF];   // 32 KB total

    // staged window start for this wave's segment (all reads in-image)
    const int W = min(SEGW * wv, IMW - WINF); // {0,104,208,256}

    // per-lane global source addresses (chunk0; chunk1 = +64 floats)
    const float* __restrict__ gx = X + b * (IMH * IMW) + y0 * IMW + W + ln;
    const float* __restrict__ gy = Y + b * (IMH * IMW) + y0 * IMW + W + ln;
    float* const lx = &lds[wv][0][0][0];      // wave-uniform LDS bases
    float* const ly = &lds[wv][1][0][0];

    // compute-side column mapping
    const int ce   = wv * SEGW + g4 * 26 + 2 * j;   // global even col
    const int lidx = min(ce, IMW - 2) - W;          // local float idx (even)
    const float2 vmask = make_float2(
        ((j <= 12) && (ce     < OW)) ? 1.f : 0.f,
        ((j <= 12) && (ce + 1 < OW)) ? 1.f : 0.f);

    // finish data_range load (and its waitcnt) BEFORE any DMA
    const float L  = data_range[b];
    const float C1 = (0.01f * L) * (0.01f * L);
    const float C2 = (0.03f * L) * (0.03f * L);
    asm volatile("" :: "v"(C1), "v"(C2));
    __builtin_amdgcn_sched_barrier(0);

    // ---- prologue: DMA rows 0..LA-1 (4 DMAs per row) ----
    #pragma unroll
    for (int k = 0; k < LA; ++k) {
        stage4(gx + k * IMW,      &lx[k * WINF]);
        stage4(gx + k * IMW + 64, &lx[k * WINF + 64]);
        stage4(gy + k * IMW,      &ly[k * WINF]);
        stage4(gy + k * IMW + 64, &ly[k * WINF + 64]);
    }

    const float inv49 = 1.0f / 49.0f;
    const float covn  = 49.0f / 48.0f;

    float2 xh[7], yh[7];
    #pragma unroll
    for (int k = 0; k < 7; ++k) { xh[k] = f2s(0.f); yh[k] = f2s(0.f); }
    float2 V0 = f2s(0.f), V1 = f2s(0.f), V2 = f2s(0.f),
           V3 = f2s(0.f), V4 = f2s(0.f);
    float2 ls2 = f2s(0.f);

    static_assert(INROWS == 27 && LA == 6 && RING == 8, "wait ladder");

    #pragma unroll
    for (int r = 0; r < INROWS; ++r) {
        // issue DMAs for row r+LA into slot (r+LA)%RING
        // (overwrites slot of row r-2: consumed two iterations ago)
        if (r + LA < INROWS) {
            const int s = (r + LA) % RING;
            stage4(gx + (r + LA) * IMW,      &lx[s * WINF]);
            stage4(gx + (r + LA) * IMW + 64, &lx[s * WINF + 64]);
            stage4(gy + (r + LA) * IMW,      &ly[s * WINF]);
            stage4(gy + (r + LA) * IMW + 64, &ly[s * WINF + 64]);
        }

        // wait for OWN row-r DMAs (4 per row); never 0 mid-loop
        if      (r < 21)  WAITV(24);
        else if (r == 21) WAITV(20);
        else if (r == 22) WAITV(16);
        else if (r == 23) WAITV(12);
        else if (r == 24) WAITV(8);
        else if (r == 25) WAITV(4);
        else              WAITV(0);

        // compute row r from private slot r%RING — no barrier needed
        const float2 x = *(const float2*)&lds[wv][0][r % RING][lidx];
        const float2 y = *(const float2*)&lds[wv][1][r % RING][lidx];

        const int ks = r % 7;                          // static after unroll
        const float2 xo = xh[ks], yo = yh[ks];
        V0 = f2add(V0, f2sub(x, xo));
        V1 = f2add(V1, f2sub(y, yo));
        V2 = f2fma(x, x, V2);  V2 = f2fnma(xo, xo, V2);
        V3 = f2fma(x, y, V3);  V3 = f2fnma(xo, yo, V3);
        V4 = f2fma(y, y, V4);  V4 = f2fnma(yo, yo, V4);
        xh[ks] = x; yh[ks] = y;

        if (r >= 6) {   // output row o = y0+r-6 < OH by tiling
            const float2 Vv[5] = {V0, V1, V2, V3, V4};
            float Se[5], So[5];
            #pragma unroll
            for (int p = 0; p < 5; ++p) {
                const float e  = Vv[p].x;
                const float o  = Vv[p].y;
                const float pp = e + o;
                float B = pp + dpp_sh<0x101>(pp);      // pp(l)+pp(l+1)
                float C = B + dpp_sh<0x102>(B);        // pp(l..l+3)
                Se[p] = C - dpp_sh<0x103>(o);          // cols 2l..2l+6
                So[p] = C - e;                         // cols 2l+1..2l+7
            }
            const float2 S0 = make_float2(Se[0], So[0]);
            const float2 S1 = make_float2(Se[1], So[1]);
            const float2 S2 = make_float2(Se[2], So[2]);
            const float2 S3 = make_float2(Se[3], So[3]);
            const float2 S4 = make_float2(Se[4], So[4]);

            float2 ux   = f2mul(S0, f2s(inv49));
            float2 uy   = f2mul(S1, f2s(inv49));
            float2 uxux = f2mul(ux, ux);
            float2 uyuy = f2mul(uy, uy);
            float2 uxuy = f2mul(ux, uy);
            float2 vx   = f2mul(f2fms(S2, inv49, uxux), f2s(covn));
            float2 vy   = f2mul(f2fms(S4, inv49, uyuy), f2s(covn));
            float2 vxy  = f2mul(f2fms(S3, inv49, uxuy), f2s(covn));
            float2 N1   = f2fma(f2s(2.f), uxuy, f2s(C1));
            float2 N2   = f2fma(f2s(2.f), vxy, f2s(C2));
            float2 D1   = f2add(f2add(uxux, uyuy), f2s(C1));
            float2 D2   = f2add(f2add(vx, vy), f2s(C2));
            float2 num  = f2mul(N1, N2);
            float2 den  = f2mul(D1, D2);
            const float rdd = __builtin_amdgcn_rcpf(den.x * den.y);
            float2 s2 = make_float2(num.x * den.y * rdd,
                                    num.y * den.x * rdd);
            ls2 = f2fma(s2, vmask, ls2);
        }
    }

    // ---- per-wave reduce -> tiny LDS -> one store per block ----
    float lsum = ls2.x + ls2.y;
    #pragma unroll
    for (int off = 32; off > 0; off >>= 1)
        lsum += __shfl_down(lsum, off, 64);
    __syncthreads();                          // main loop fully done
    if (ln == 0) ((float*)lds)[wv] = lsum;
    __syncthreads();
    if (tid == 0) {
        partials[b * NSTRIP + strip] = ((float*)lds)[0] + ((float*)lds)[1]
                                     + ((float*)lds)[2] + ((float*)lds)[3];
    }
}

__global__ void finalize_kernel(const float* __restrict__ partials,
                                float* __restrict__ out)
{
    float v = 0.f;
    #pragma unroll
    for (int k = 0; k < NSTRIP; ++k)
        v += partials[threadIdx.x + 64 * k];
    #pragma unroll
    for (int off = 32; off > 0; off >>= 1)
        v += __shfl_down(v, off, 64);
    if (threadIdx.x == 0)
        out[0] = 1.0f - v * (1.0f / (float)(NB * OH * OW));
}

extern "C" void kernel_launch(void* const* d_in, const int* in_sizes, int n_in,
                              void* d_out, int out_size, void* d_ws, size_t ws_size,
                              hipStream_t stream) {
    const float* X  = (const float*)d_in[0];
    const float* Y  = (const float*)d_in[1];
    const float* dr = (const float*)d_in[2];
    float* out = (float*)d_out;
    float* partials = (float*)d_ws;           // NB*NSTRIP floats, fully written

    dim3 grid(NSTRIP, NB);      // 18 x 64 = 1152 blocks, 4 wave-tasks each
    dim3 block(BLOCK);          // 256 threads = 4 independent waves
    ssim_kernel<<<grid, block, 0, stream>>>(X, Y, dr, partials);
    finalize_kernel<<<1, 64, 0, stream>>>(partials, out);
}

// Round 10
// 34.091 us; speedup vs baseline: 1.0681x; 1.0681x over previous
//
#include <hip/hip_runtime.h>

#define IMH 384
#define IMW 384
#define OH 378
#define OW 378
#define NB 64
#define SROWS 21
#define INROWS 27          // SROWS + 6
#define NSTRIP 18          // 18*21 = 378 exactly
#define NSEG4 4            // column segments (one wave each)
#define BLOCK 64           // ONE wave per block: fully independent task
#define WINF 128           // staged floats per row per tensor
#define NPAIR 14           // staged row-pairs (28 rows; row 27 = clamped pad)
#define NPART (NB * NSEG4 * NSTRIP)   // 4608 partials

// Round 19: R18 finally got clean ssim counters: VALUBusy 35%, HBM 14%,
// Occupancy 28% (~9 waves/CU), conflicts 0 -> latency/occupancy-bound,
// definitively. R18's own regression vs R17: 4x DMA instr count (4B grain),
// 1.33x horiz staging redundancy, and the per-row WAITV memory clobber
// serializing ds_read (120cy) + VALU chain (~150cy) every row.
// Fixes, keeping the de-phased wave-independent design:
//  1. 16B DMAs staging a ROW PAIR per instr (lanes 0-31 row 2p, lanes
//     32-63 row 2p+1; per-lane global addr, linear 1KB LDS slot).
//     28 DMA instrs/wave (was 108), 1KB requests.
//  2. Software-pipelined LDS reads: wait+read pair p+1 into next-regs,
//     compute pair p from cur-regs -> ds_read latency hidden.
//  3. Single-wave blocks: 8KB LDS ring (4 pair-slots x 2 tensors), grid
//     4608 -> ~18 waves/CU (2x R18's 9), LDS cap 20/CU, zero barriers.
// Ladder: steady outstanding = 3 pairs x 2 = 6 instrs; WAITV(4) per pair;
// tail 2/0. Row 27 staged clamped (strip 17), statically never computed.
// PRED: WG 64, LDS 8192, VGPR 85-102, Occ 45-60%, VALUBusy 55-75%,
// dur 28.2 -> 16-21us. Flat at >=26 kills the chain model -> R20 ablation.

template <int CTRL>
__device__ __forceinline__ float dpp_sh(float v) {
    return __int_as_float(__builtin_amdgcn_update_dpp(
        0, __float_as_int(v), CTRL, 0xf, 0xf, true));
}

__device__ __forceinline__ float2 f2add(float2 a, float2 b) { return make_float2(a.x + b.x, a.y + b.y); }
__device__ __forceinline__ float2 f2sub(float2 a, float2 b) { return make_float2(a.x - b.x, a.y - b.y); }
__device__ __forceinline__ float2 f2mul(float2 a, float2 b) { return make_float2(a.x * b.x, a.y * b.y); }
__device__ __forceinline__ float2 f2fma(float2 a, float2 b, float2 c) {
    return make_float2(fmaf(a.x, b.x, c.x), fmaf(a.y, b.y, c.y));
}
__device__ __forceinline__ float2 f2fnma(float2 a, float2 b, float2 c) {  // c - a*b
    return make_float2(fmaf(-a.x, b.x, c.x), fmaf(-a.y, b.y, c.y));
}
__device__ __forceinline__ float2 f2fms(float2 a, float s, float2 c) {    // a*s - c
    return make_float2(fmaf(a.x, s, -c.x), fmaf(a.y, s, -c.y));
}
__device__ __forceinline__ float2 f2s(float s) { return make_float2(s, s); }

// async global->LDS DMA, 16B per lane; dest = wave-uniform base + lane*16B
__device__ __forceinline__ void stage16(const float* g, float* l) {
    __builtin_amdgcn_global_load_lds(
        (const __attribute__((address_space(1))) uint32_t*)(g),
        (__attribute__((address_space(3))) uint32_t*)(l),
        16, 0, 0);
}

#define WAITV(n) asm volatile("s_waitcnt vmcnt(" #n ")" ::: "memory")

__global__ __launch_bounds__(BLOCK)
__attribute__((amdgpu_waves_per_eu(5, 8)))
void ssim_kernel(
    const float* __restrict__ X, const float* __restrict__ Y,
    const float* __restrict__ data_range, float* __restrict__ partials)
{
    const int ln    = threadIdx.x;            // lane 0..63
    const int g4    = ln >> 4;                // DPP group 0..3
    const int j     = ln & 15;                // lane within group
    const int strip = blockIdx.x;
    const int seg   = blockIdx.y;
    const int b     = blockIdx.z;
    const int y0    = strip * SROWS;          // <= 357

    // pair-slot ring: [slot][row-in-pair][floats]; 4KB per tensor
    __shared__ __align__(16) float ldsX[4][2][WINF];
    __shared__ __align__(16) float ldsY[4][2][WINF];

    // staged window start (all reads in-image): {0,104,208,256}
    const int W = min(104 * seg, IMW - WINF);

    // per-lane DMA source: lanes 0-31 -> row 2p, lanes 32-63 -> row 2p+1
    const int c4 = (ln & 31) * 4;             // float col within window
    const int hr = ln >> 5;                   // row within pair
    const float* __restrict__ gx = X + b * (IMH * IMW) + (y0 + hr) * IMW + W + c4;
    const float* __restrict__ gy = Y + b * (IMH * IMW) + (y0 + hr) * IMW + W + c4;
    // clamped base for pair 13 (row y0+27 may be 384 on the last strip)
    const int r13 = min(y0 + 26 + hr, IMH - 1);
    const float* __restrict__ gx13 = X + b * (IMH * IMW) + r13 * IMW + W + c4;
    const float* __restrict__ gy13 = Y + b * (IMH * IMW) + r13 * IMW + W + c4;

    // compute-side column mapping
    const int ce   = seg * 104 + g4 * 26 + 2 * j;   // global even col
    const int lidx = min(ce, IMW - 2) - W;          // local float idx (even)
    const float2 vmask = make_float2(
        ((j <= 12) && (ce     < OW)) ? 1.f : 0.f,
        ((j <= 12) && (ce + 1 < OW)) ? 1.f : 0.f);

    // finish data_range load (and its waitcnt) BEFORE any DMA
    const float L  = data_range[b];
    const float C1 = (0.01f * L) * (0.01f * L);
    const float C2 = (0.03f * L) * (0.03f * L);
    asm volatile("" :: "v"(C1), "v"(C2));
    __builtin_amdgcn_sched_barrier(0);

    // ---- prologue: DMA pairs 0,1,2 (6 instrs; X,Y per pair) ----
    #pragma unroll
    for (int k = 0; k < 3; ++k) {
        stage16(gx + 2 * k * IMW, &ldsX[k][0][0]);
        stage16(gy + 2 * k * IMW, &ldsY[k][0][0]);
    }
    WAITV(4);                                 // pair 0 complete
    float2 cx0 = *(const float2*)&ldsX[0][0][lidx];
    float2 cx1 = *(const float2*)&ldsX[0][1][lidx];
    float2 cy0 = *(const float2*)&ldsY[0][0][lidx];
    float2 cy1 = *(const float2*)&ldsY[0][1][lidx];

    const float inv49 = 1.0f / 49.0f;
    const float covn  = 49.0f / 48.0f;

    float2 xh[7], yh[7];
    #pragma unroll
    for (int k = 0; k < 7; ++k) { xh[k] = f2s(0.f); yh[k] = f2s(0.f); }
    float2 V0 = f2s(0.f), V1 = f2s(0.f), V2 = f2s(0.f),
           V3 = f2s(0.f), V4 = f2s(0.f);
    float2 ls2 = f2s(0.f);

    static_assert(INROWS == 27 && NPAIR == 14, "ladder");

    #pragma unroll
    for (int p = 0; p < NPAIR; ++p) {
        // issue DMA for pair p+3 into slot (p+3)&3 (overwrites pair p-1,
        // whose reads completed at iter p-1; program order guarantees safety)
        if (p + 3 < NPAIR) {
            const float* sx = (p + 3 == 13) ? gx13 : gx + 2 * (p + 3) * IMW;
            const float* sy = (p + 3 == 13) ? gy13 : gy + 2 * (p + 3) * IMW;
            stage16(sx, &ldsX[(p + 3) & 3][0][0]);
            stage16(sy, &ldsY[(p + 3) & 3][0][0]);
        }

        // wait for pair p+1, read it into next-regs (latency hides under
        // the pair-p compute below); never drain vmcnt mid-loop
        float2 nx0, nx1, ny0, ny1;
        if (p + 1 < NPAIR) {
            if      (p <= 10) WAITV(4);
            else if (p == 11) WAITV(2);
            else              WAITV(0);
            nx0 = *(const float2*)&ldsX[(p + 1) & 3][0][lidx];
            nx1 = *(const float2*)&ldsX[(p + 1) & 3][1][lidx];
            ny0 = *(const float2*)&ldsY[(p + 1) & 3][0][lidx];
            ny1 = *(const float2*)&ldsY[(p + 1) & 3][1][lidx];
        }

        // compute the two rows of pair p from cur-regs (register-only)
        #pragma unroll
        for (int h = 0; h < 2; ++h) {
            const int r = 2 * p + h;
            if (r < INROWS) {
                const float2 x = h ? cx1 : cx0;
                const float2 y = h ? cy1 : cy0;

                const int ks = r % 7;                  // static after unroll
                const float2 xo = xh[ks], yo = yh[ks];
                V0 = f2add(V0, f2sub(x, xo));
                V1 = f2add(V1, f2sub(y, yo));
                V2 = f2fma(x, x, V2);  V2 = f2fnma(xo, xo, V2);
                V3 = f2fma(x, y, V3);  V3 = f2fnma(xo, yo, V3);
                V4 = f2fma(y, y, V4);  V4 = f2fnma(yo, yo, V4);
                xh[ks] = x; yh[ks] = y;

                if (r >= 6) {   // output row o = y0+r-6 < OH by tiling
                    const float2 Vv[5] = {V0, V1, V2, V3, V4};
                    float Se[5], So[5];
                    #pragma unroll
                    for (int q = 0; q < 5; ++q) {
                        const float e  = Vv[q].x;
                        const float o  = Vv[q].y;
                        const float pp = e + o;
                        float B = pp + dpp_sh<0x101>(pp);  // pp(l)+pp(l+1)
                        float C = B + dpp_sh<0x102>(B);    // pp(l..l+3)
                        Se[q] = C - dpp_sh<0x103>(o);      // cols 2l..2l+6
                        So[q] = C - e;                     // cols 2l+1..2l+7
                    }
                    const float2 S0 = make_float2(Se[0], So[0]);
                    const float2 S1 = make_float2(Se[1], So[1]);
                    const float2 S2 = make_float2(Se[2], So[2]);
                    const float2 S3 = make_float2(Se[3], So[3]);
                    const float2 S4 = make_float2(Se[4], So[4]);

                    float2 ux   = f2mul(S0, f2s(inv49));
                    float2 uy   = f2mul(S1, f2s(inv49));
                    float2 uxux = f2mul(ux, ux);
                    float2 uyuy = f2mul(uy, uy);
                    float2 uxuy = f2mul(ux, uy);
                    float2 vx   = f2mul(f2fms(S2, inv49, uxux), f2s(covn));
                    float2 vy   = f2mul(f2fms(S4, inv49, uyuy), f2s(covn));
                    float2 vxy  = f2mul(f2fms(S3, inv49, uxuy), f2s(covn));
                    float2 N1   = f2fma(f2s(2.f), uxuy, f2s(C1));
                    float2 N2   = f2fma(f2s(2.f), vxy, f2s(C2));
                    float2 D1   = f2add(f2add(uxux, uyuy), f2s(C1));
                    float2 D2   = f2add(f2add(vx, vy), f2s(C2));
                    float2 num  = f2mul(N1, N2);
                    float2 den  = f2mul(D1, D2);
                    const float rdd = __builtin_amdgcn_rcpf(den.x * den.y);
                    float2 s2 = make_float2(num.x * den.y * rdd,
                                            num.y * den.x * rdd);
                    ls2 = f2fma(s2, vmask, ls2);
                }
            }
        }

        if (p + 1 < NPAIR) { cx0 = nx0; cx1 = nx1; cy0 = ny0; cy1 = ny1; }
    }

    // ---- single-wave reduce -> one plain store per block ----
    float lsum = ls2.x + ls2.y;
    #pragma unroll
    for (int off = 32; off > 0; off >>= 1)
        lsum += __shfl_down(lsum, off, 64);
    if (ln == 0)
        partials[(b * NSEG4 + seg) * NSTRIP + strip] = lsum;
}

__global__ void finalize_kernel(const float* __restrict__ partials,
                                float* __restrict__ out)
{
    // 64 threads reduce NPART = 4608 partials (72 each)
    float v = 0.f;
    #pragma unroll
    for (int k = 0; k < NPART / 64; ++k)
        v += partials[threadIdx.x + 64 * k];
    #pragma unroll
    for (int off = 32; off > 0; off >>= 1)
        v += __shfl_down(v, off, 64);
    if (threadIdx.x == 0)
        out[0] = 1.0f - v * (1.0f / (float)(NB * OH * OW));
}

extern "C" void kernel_launch(void* const* d_in, const int* in_sizes, int n_in,
                              void* d_out, int out_size, void* d_ws, size_t ws_size,
                              hipStream_t stream) {
    const float* X  = (const float*)d_in[0];
    const float* Y  = (const float*)d_in[1];
    const float* dr = (const float*)d_in[2];
    float* out = (float*)d_out;
    float* partials = (float*)d_ws;           // NPART floats, fully written

    dim3 grid(NSTRIP, NSEG4, NB);   // 18 x 4 x 64 = 4608 single-wave blocks
    dim3 block(BLOCK);              // 64 threads = 1 wave
    ssim_kernel<<<grid, block, 0, stream>>>(X, Y, dr, partials);
    finalize_kernel<<<1, 64, 0, stream>>>(partials, out);
}

// Round 11
// 27.933 us; speedup vs baseline: 1.3037x; 1.2205x over previous
//
#include <hip/hip_runtime.h>

#define IMH 384
#define IMW 384
#define OH 378
#define OW 378
#define NB 64
#define SROWS 21
#define INROWS 27          // computed rows per strip (27 = 21 + 6)
#define NSTRIP 18          // 18*21 = 378 exactly
#define BLOCK 256          // 4 waves = 16 DPP groups of 16 lanes
#define GSTRIDE 26         // output cols per group (13 lanes x 2 cols)
#define NPAIR 14           // staged row-pairs (28 rows; row 27 = clamped pad)
#define SLOTF 512          // floats per row: 384 data + 128 pad (2048 B)

// Round 20: R18/R19 (wave-independent rings) both LOST to R17's 4-wave
// barriered DMA ring (36.4/34.1 vs 28.2) -> de-phasing doesn't pay; its
// redundancy + DMA-instr overhead cost more. R18's capture (VALU 35%,
// HBM 14%, Occ 28%) stands: latency kernel, both pipes idle.
// R17's residual: per-row serial chain x27 — WAITV -> s_barrier ->
// ds_read (~120cy, UNHIDDEN: used immediately) -> dependent VALU; 27
// barriers of skew. Fix, keeping R17's staging shell verbatim:
//  1. Pair-phases: 14 barriers instead of 27.
//  2. Software pipeline: read pair p into next-regs, compute pair p-1
//     from cur-regs -> ds_read latency hides under ~500cy of compute.
//  3. Race-free slot reuse: DMA(p+3) -> slot (p-1)&3 issued AFTER
//     compute(p-1) lgkm-drained that slot. Lookahead 3 iters >= HBM lat.
//  4. Wait ladder: steady vmcnt(4), tail 4/2/0 — never drains mid-loop.
// PRED: LDS 32768, VGPR 70-90, dur 28.2 -> 23-25.5us. Flat >=27 ->
// scheduling family exhausted; R21 = tile-shape / memory-queue angle.

template <int CTRL>
__device__ __forceinline__ float dpp_sh(float v) {
    return __int_as_float(__builtin_amdgcn_update_dpp(
        0, __float_as_int(v), CTRL, 0xf, 0xf, true));
}

__device__ __forceinline__ float2 f2add(float2 a, float2 b) { return make_float2(a.x + b.x, a.y + b.y); }
__device__ __forceinline__ float2 f2sub(float2 a, float2 b) { return make_float2(a.x - b.x, a.y - b.y); }
__device__ __forceinline__ float2 f2mul(float2 a, float2 b) { return make_float2(a.x * b.x, a.y * b.y); }
__device__ __forceinline__ float2 f2fma(float2 a, float2 b, float2 c) {
    return make_float2(fmaf(a.x, b.x, c.x), fmaf(a.y, b.y, c.y));
}
__device__ __forceinline__ float2 f2fnma(float2 a, float2 b, float2 c) {  // c - a*b
    return make_float2(fmaf(-a.x, b.x, c.x), fmaf(-a.y, b.y, c.y));
}
__device__ __forceinline__ float2 f2fms(float2 a, float s, float2 c) {    // a*s - c
    return make_float2(fmaf(a.x, s, -c.x), fmaf(a.y, s, -c.y));
}
__device__ __forceinline__ float2 f2s(float s) { return make_float2(s, s); }

// async global->LDS DMA, 16B per lane; dest = wave-uniform base + lane*16B
__device__ __forceinline__ void stage16(const float* g, float* l) {
    __builtin_amdgcn_global_load_lds(
        (const __attribute__((address_space(1))) uint32_t*)(g),
        (__attribute__((address_space(3))) uint32_t*)(l),
        16, 0, 0);
}

#define WAITV(n) asm volatile("s_waitcnt vmcnt(" #n ")" ::: "memory")
#define RAWBAR() asm volatile("s_barrier" ::: "memory")

__global__ __launch_bounds__(BLOCK)
__attribute__((amdgpu_waves_per_eu(5, 8)))
void ssim_kernel(
    const float* __restrict__ X, const float* __restrict__ Y,
    const float* __restrict__ data_range, float* __restrict__ partials)
{
    const int tid   = threadIdx.x;
    const int g     = tid >> 4;               // DPP group 0..15
    const int j     = tid & 15;               // lane within group
    const int strip = blockIdx.x;
    const int b     = blockIdx.y;
    const int y0    = strip * SROWS;          // <= 357

    // pair-slot ring: [pairslot][row-in-pair][floats]; 16 KB per tensor
    __shared__ float sX[4][2][SLOTF];
    __shared__ float sY[4][2][SLOTF];

    // ---- staging role (R17 shell): wv0=X-lo wv1=X-hi wv2=Y-lo wv3=Y-hi
    const int wv   = tid >> 6;
    const int ln   = tid & 63;
    const bool isX = (wv < 2);
    const int half = wv & 1;                  // 0: floats 0..255, 1: 256..511
    const int foff = half * 256 + ln * 4;     // float col of this lane's 16B
    const int fcl  = min(foff, IMW - 4);      // pad lanes re-read last 16B
    const float* __restrict__ gstg =
        (isX ? X : Y) + b * (IMH * IMW) + y0 * IMW + fcl;
    const float* __restrict__ gstg27 =        // row 27, clamped (strip 17)
        (isX ? X : Y) + b * (IMH * IMW) + min(y0 + 27, IMH - 1) * IMW + fcl;
    float* const lbase = (isX ? &sX[0][0][0] : &sY[0][0][0]) + foff;

    // compute-side column mapping (unchanged from R17)
    const int ce  = g * GSTRIDE + 2 * j;      // lane's even column (global)
    const int cin = min(ce, IMW - 2);         // clamped, even -> 8B aligned
    const float2 vmask = make_float2(
        ((j <= 12) && (ce     < OW)) ? 1.f : 0.f,
        ((j <= 12) && (ce + 1 < OW)) ? 1.f : 0.f);

    // finish data_range load (and its compiler waitcnt) BEFORE any DMA
    const float L  = data_range[b];
    const float C1 = (0.01f * L) * (0.01f * L);
    const float C2 = (0.03f * L) * (0.03f * L);
    asm volatile("" :: "v"(C1), "v"(C2));
    __builtin_amdgcn_sched_barrier(0);

    // ---- prologue: DMA pairs 0..3 (8 instrs/wave) ----
    #pragma unroll
    for (int q = 0; q < 4; ++q) {
        stage16(gstg + (2 * q) * IMW,     lbase + (2 * q + 0) * SLOTF);
        stage16(gstg + (2 * q + 1) * IMW, lbase + (2 * q + 1) * SLOTF);
    }
    WAITV(6);                                 // pair 0 complete (own)
    RAWBAR();                                 // all waves' pair 0 complete
    float2 cx0 = *(const float2*)&sX[0][0][cin];
    float2 cx1 = *(const float2*)&sX[0][1][cin];
    float2 cy0 = *(const float2*)&sY[0][0][cin];
    float2 cy1 = *(const float2*)&sY[0][1][cin];

    const float inv49 = 1.0f / 49.0f;
    const float covn  = 49.0f / 48.0f;

    float2 xh[7], yh[7];
    #pragma unroll
    for (int k = 0; k < 7; ++k) { xh[k] = f2s(0.f); yh[k] = f2s(0.f); }
    float2 V0 = f2s(0.f), V1 = f2s(0.f), V2 = f2s(0.f),
           V3 = f2s(0.f), V4 = f2s(0.f);
    float2 ls2 = f2s(0.f);

    auto rowcompute = [&](int r, float2 x, float2 y) {
        const int ks = r % 7;                          // static after unroll
        const float2 xo = xh[ks], yo = yh[ks];
        V0 = f2add(V0, f2sub(x, xo));
        V1 = f2add(V1, f2sub(y, yo));
        V2 = f2fma(x, x, V2);  V2 = f2fnma(xo, xo, V2);
        V3 = f2fma(x, y, V3);  V3 = f2fnma(xo, yo, V3);
        V4 = f2fma(y, y, V4);  V4 = f2fnma(yo, yo, V4);
        xh[ks] = x; yh[ks] = y;

        if (r >= 6) {   // output row o = y0+r-6 < OH by tiling
            const float2 Vv[5] = {V0, V1, V2, V3, V4};
            float Se[5], So[5];
            #pragma unroll
            for (int q = 0; q < 5; ++q) {
                const float e  = Vv[q].x;
                const float o  = Vv[q].y;
                const float pp = e + o;
                float B = pp + dpp_sh<0x101>(pp);      // pp(l)+pp(l+1)
                float C = B + dpp_sh<0x102>(B);        // pp(l..l+3)
                Se[q] = C - dpp_sh<0x103>(o);          // cols 2l..2l+6
                So[q] = C - e;                         // cols 2l+1..2l+7
            }
            const float2 S0 = make_float2(Se[0], So[0]);
            const float2 S1 = make_float2(Se[1], So[1]);
            const float2 S2 = make_float2(Se[2], So[2]);
            const float2 S3 = make_float2(Se[3], So[3]);
            const float2 S4 = make_float2(Se[4], So[4]);

            float2 ux   = f2mul(S0, f2s(inv49));
            float2 uy   = f2mul(S1, f2s(inv49));
            float2 uxux = f2mul(ux, ux);
            float2 uyuy = f2mul(uy, uy);
            float2 uxuy = f2mul(ux, uy);
            float2 vx   = f2mul(f2fms(S2, inv49, uxux), f2s(covn));
            float2 vy   = f2mul(f2fms(S4, inv49, uyuy), f2s(covn));
            float2 vxy  = f2mul(f2fms(S3, inv49, uxuy), f2s(covn));
            float2 N1   = f2fma(f2s(2.f), uxuy, f2s(C1));
            float2 N2   = f2fma(f2s(2.f), vxy, f2s(C2));
            float2 D1   = f2add(f2add(uxux, uyuy), f2s(C1));
            float2 D2   = f2add(f2add(vx, vy), f2s(C2));
            float2 num  = f2mul(N1, N2);
            float2 den  = f2mul(D1, D2);
            const float rdd = __builtin_amdgcn_rcpf(den.x * den.y);
            float2 s2 = make_float2(num.x * den.y * rdd,
                                    num.y * den.x * rdd);
            ls2 = f2fma(s2, vmask, ls2);
        }
    };

    static_assert(INROWS == 27 && NPAIR == 14, "ladder");

    #pragma unroll
    for (int p = 1; p < NPAIR; ++p) {
        // wait own pair-p DMAs (outstanding before: pairs p..p+2 = 6)
        if      (p <= 11) WAITV(4);
        else if (p == 12) WAITV(2);
        else              WAITV(0);
        RAWBAR();                             // all waves' pair p complete

        // read pair p into next-regs (latency hides under pair p-1 compute)
        const int sl = p & 3;
        float2 nx0 = *(const float2*)&sX[sl][0][cin];
        float2 nx1 = *(const float2*)&sX[sl][1][cin];
        float2 ny0 = *(const float2*)&sY[sl][0][cin];
        float2 ny1 = *(const float2*)&sY[sl][1][cin];

        // compute pair p-1 (lgkm-drains cur's reads from slot (p-1)&3)
        rowcompute(2 * (p - 1),     cx0, cy0);
        rowcompute(2 * (p - 1) + 1, cx1, cy1);

        // issue DMA pair p+3 into slot (p+3)&3 == (p-1)&3: its previous
        // reads were consumed just above -> race-free by program order.
        if (p + 3 < NPAIR) {
            const int q = p + 3;
            const float* s1 = (q == 13) ? gstg27 : gstg + (2 * q + 1) * IMW;
            stage16(gstg + (2 * q) * IMW, lbase + ((q & 3) * 2 + 0) * SLOTF);
            stage16(s1,                   lbase + ((q & 3) * 2 + 1) * SLOTF);
        }

        cx0 = nx0; cx1 = nx1; cy0 = ny0; cy1 = ny1;
    }

    // epilogue: pair 13 = rows 26 (row 27 is clamped pad, never computed)
    rowcompute(26, cx0, cy0);

    // ---- block reduction -> plain store (reuse sX; loop fully done) ----
    float lsum = ls2.x + ls2.y;
    #pragma unroll
    for (int off = 32; off > 0; off >>= 1)
        lsum += __shfl_down(lsum, off, 64);
    __syncthreads();
    if ((tid & 63) == 0) sX[0][0][tid >> 6] = lsum;
    __syncthreads();
    if (tid == 0) {
        partials[b * NSTRIP + strip] =
            sX[0][0][0] + sX[0][0][1] + sX[0][0][2] + sX[0][0][3];
    }
}

__global__ void finalize_kernel(const float* __restrict__ partials,
                                float* __restrict__ out)
{
    float v = 0.f;
    #pragma unroll
    for (int k = 0; k < NSTRIP; ++k)
        v += partials[threadIdx.x + 64 * k];
    #pragma unroll
    for (int off = 32; off > 0; off >>= 1)
        v += __shfl_down(v, off, 64);
    if (threadIdx.x == 0)
        out[0] = 1.0f - v * (1.0f / (float)(NB * OH * OW));
}

extern "C" void kernel_launch(void* const* d_in, const int* in_sizes, int n_in,
                              void* d_out, int out_size, void* d_ws, size_t ws_size,
                              hipStream_t stream) {
    const float* X  = (const float*)d_in[0];
    const float* Y  = (const float*)d_in[1];
    const float* dr = (const float*)d_in[2];
    float* out = (float*)d_out;
    float* partials = (float*)d_ws;           // NB*NSTRIP floats, fully written

    dim3 grid(NSTRIP, NB);      // 18 x 64 = 1152 blocks
    dim3 block(BLOCK);          // 256 threads = 4 waves
    ssim_kernel<<<grid, block, 0, stream>>>(X, Y, dr, partials);
    finalize_kernel<<<1, 64, 0, stream>>>(partials, out);
}